// Round 14
// baseline (300.448 us; speedup 1.0000x reference)
//
#include <hip/hip_runtime.h>

// RelationNetwork fused pipeline for MI355X (gfx950).
// B=64, N=64, D=64, T=128, HG=256, HF=128, OUT=128. M = B*N*N = 262144 pair rows.
//
// Pipeline (9 dispatches):
//  k_wt     : gW1->W1T, gW2->W2T (f16 [n][k]) + zero stats region
//  k_prep   : U = x@W0[:64], V = x@W0[64:]  (fp32) + fused per-b column stats -> st0
//  k_uv     : [bn0 closed-form preamble] U' = c0s*U + c0t, V' = c0s*V (f16)
//  k_gemm1  : Z1 = relu(U'+V') @ W1 + b1 -> fp8 (r8 loop; f32 two-half epilogue)
//  k_gemm2  : [bn1 preamble] a1 = relu(bn1(Z1_fp8)) staged f16 (packed math),
//             z2 = a1 @ W2 (f16 MFMA) -> fp8 Z2 (f32 two-half epilogue) + stats
//  k_red    : [bn2 preamble] stream fp8 Z2, bn2+relu, row-reduce -> sbuf
//  k_fg x3  : F MLP GEMMs (bn-fold preambles, 8-block parallel)
//
// Lessons encoded:
//  - r5/r9/r10: gemm1 loop-structure changes fail 3x. r8 loop = local optimum.
//  - r6: a0 precompute into LDS removes VALU from MFMA loop (89->70 us).
//  - r7: dispatch gaps ~2.4us each; 1-block BN kernels fused into consumers.
//  - r11: one fp8 quant per tensor per hop is the accuracy budget.
//  - r13/r14: the VALU hog is conversion work, not a0: packed-f16 staging
//    (gemm2, -8us) and f32 epilogue (no f16 round-trip: 128 fewer cvts/thread).

typedef _Float16 half8 __attribute__((ext_vector_type(8)));
typedef _Float16 half4_t __attribute__((ext_vector_type(4)));
typedef __fp16 fp16x2 __attribute__((ext_vector_type(2)));
typedef float float4_t __attribute__((ext_vector_type(4)));
typedef float float2_t __attribute__((ext_vector_type(2)));
typedef unsigned int uint2_t __attribute__((ext_vector_type(2)));

static constexpr float kEps = 1e-5f;
static constexpr float kM = 262144.f;

// ---- workspace layout (bytes) ----
static constexpr size_t OFF_U   = 0;                                  // 4096*256 f32
static constexpr size_t OFF_V   = OFF_U  + (size_t)4096*256*4;
static constexpr size_t OFF_UP  = OFF_V  + (size_t)4096*256*4;        // f16
static constexpr size_t OFF_VP  = OFF_UP + (size_t)4096*256*2;
static constexpr size_t OFF_W1T = OFF_VP + (size_t)4096*256*2;        // 256x256 f16 [n][k]
static constexpr size_t OFF_W2T = OFF_W1T + (size_t)256*256*2;        // 128x256 f16 [n][k]
static constexpr size_t OFF_Z1  = OFF_W2T + (size_t)128*256*2;        // 262144x256 fp8
// ---- zeroed region start (zeroed by k_wt every launch) ----
static constexpr size_t OFF_ST0 = OFF_Z1 + (size_t)262144*256;        // 64*4*256 f32 (atomics)
static constexpr size_t OFF_ST1 = OFF_ST0 + (size_t)64*4*256*4;       // 32*512 f32
static constexpr size_t OFF_ST2 = OFF_ST1 + (size_t)32*512*4;         // 32*256 f32
static constexpr size_t OFF_SB  = OFF_ST2 + (size_t)32*256*4;         // 64*128 f32
static constexpr size_t OFF_FST0 = OFF_SB + (size_t)64*128*4;         // 256 f32
static constexpr size_t OFF_FST1 = OFF_FST0 + 1024;                   // 256 f32
static constexpr int ZERO_FLOATS = (64*4*256 + 32*512 + 32*256 + 64*128 + 256 + 256);
// ---- end zeroed region ----
static constexpr size_t OFF_FZ0  = OFF_FST1 + 1024;                   // 64*128 f32
static constexpr size_t OFF_FZ1  = OFF_FZ0 + (size_t)64*128*4;
static constexpr size_t OFF_Z2   = OFF_FZ1 + (size_t)64*128*4;        // 262144x128 fp8

static __device__ inline half8 relu8(half8 s) {
#pragma unroll
  for (int e = 0; e < 8; ++e) s[e] = s[e] > (_Float16)0 ? s[e] : (_Float16)0;
  return s;
}

// unpack 8 fp8 e4m3 bytes -> 8 f16 (via f32, packed cvt)
static __device__ inline half8 unpack_fp8x8(uint2_t p) {
  float2_t f0 = __builtin_amdgcn_cvt_pk_f32_fp8((int)p[0], false);
  float2_t f1 = __builtin_amdgcn_cvt_pk_f32_fp8((int)p[0], true);
  float2_t f2 = __builtin_amdgcn_cvt_pk_f32_fp8((int)p[1], false);
  float2_t f3 = __builtin_amdgcn_cvt_pk_f32_fp8((int)p[1], true);
  fp16x2 h0 = __builtin_amdgcn_cvt_pkrtz(f0[0], f0[1]);
  fp16x2 h1 = __builtin_amdgcn_cvt_pkrtz(f1[0], f1[1]);
  fp16x2 h2 = __builtin_amdgcn_cvt_pkrtz(f2[0], f2[1]);
  fp16x2 h3 = __builtin_amdgcn_cvt_pkrtz(f3[0], f3[1]);
  half8 hv = {(_Float16)h0[0], (_Float16)h0[1], (_Float16)h1[0], (_Float16)h1[1],
              (_Float16)h2[0], (_Float16)h2[1], (_Float16)h3[0], (_Float16)h3[1]};
  return hv;
}

// pack 8 f32 (consecutive in LDS) -> 8 fp8 bytes
static __device__ inline uint2_t pack_fp8_from_f32(const float* src) {
  int lo = 0, hi = 0;
  lo = __builtin_amdgcn_cvt_pk_fp8_f32(src[0], src[1], lo, false);
  lo = __builtin_amdgcn_cvt_pk_fp8_f32(src[2], src[3], lo, true);
  hi = __builtin_amdgcn_cvt_pk_fp8_f32(src[4], src[5], hi, false);
  hi = __builtin_amdgcn_cvt_pk_fp8_f32(src[6], src[7], hi, true);
  uint2_t o = {(unsigned)lo, (unsigned)hi};
  return o;
}

// ---- W transpose/convert + zero the stats region
__global__ __launch_bounds__(256) void k_wt(const float* __restrict__ gW1,
                                            const float* __restrict__ gW2,
                                            _Float16* __restrict__ W1T,
                                            _Float16* __restrict__ W2T,
                                            float* __restrict__ zbuf) {
  int idx = blockIdx.x * 256 + threadIdx.x;
  if (idx < 65536) {
    int n = idx >> 8, k = idx & 255;
    W1T[idx] = (_Float16)gW1[k * 256 + n];
  } else if (idx < 98304) {
    int j = idx - 65536;
    int n = j >> 8, k = j & 255;
    W2T[j] = (_Float16)gW2[k * 128 + n];
  }
  if (idx < ZERO_FLOATS) zbuf[idx] = 0.f;
}

// ---- U = x @ W0[0:64,:], V = x @ W0[64:128,:]  (fp32) + fused column stats -> st0
__global__ __launch_bounds__(256) void k_prep(const float* __restrict__ x,
                                              const float* __restrict__ gW0,
                                              float* __restrict__ U,
                                              float* __restrict__ V,
                                              float* __restrict__ st0) {
  __shared__ __align__(16) float sX[32 * 64];
  __shared__ __align__(16) float sZ[32 * 128];
  int t = threadIdx.x;
  int p0 = blockIdx.x * 32;
  int by = blockIdx.y;
  int hsel = by >> 1;
  int cbase = (by & 1) * 128;
#pragma unroll
  for (int it = 0; it < 2; ++it) {
    int f4 = (it * 256 + t) * 4;
    *(float4_t*)(sX + f4) = *(const float4_t*)(x + (size_t)p0 * 64 + f4);
  }
  __syncthreads();
  int r = t >> 3, cg = (t & 7) * 16;
  const float* Wb = gW0 + (size_t)(hsel * 64) * 256 + cbase + cg;
  float acc[16];
#pragma unroll
  for (int j = 0; j < 16; ++j) acc[j] = 0.f;
  for (int k = 0; k < 64; ++k) {
    float xv = sX[r * 64 + k];
    const float4_t* wr = (const float4_t*)(Wb + (size_t)k * 256);
    float4_t w0 = wr[0], w1 = wr[1], w2 = wr[2], w3 = wr[3];
#pragma unroll
    for (int j = 0; j < 4; ++j) {
      acc[j]      += xv * w0[j];
      acc[4 + j]  += xv * w1[j];
      acc[8 + j]  += xv * w2[j];
      acc[12 + j] += xv * w3[j];
    }
  }
  float* outp = (hsel ? V : U) + (size_t)(p0 + r) * 256 + cbase + cg;
#pragma unroll
  for (int q = 0; q < 4; ++q) {
    float4_t o = {acc[q * 4], acc[q * 4 + 1], acc[q * 4 + 2], acc[q * 4 + 3]};
    *(float4_t*)(outp + q * 4) = o;
  }
#pragma unroll
  for (int j = 0; j < 16; ++j) sZ[r * 128 + cg + j] = acc[j];
  __syncthreads();
  if (t < 128) {
    float S = 0.f, S2 = 0.f;
#pragma unroll
    for (int rr = 0; rr < 32; ++rr) {
      float z = sZ[rr * 128 + t];
      S += z;
      S2 += z * z;
    }
    int b = blockIdx.x >> 1;
    atomicAdd(st0 + (size_t)(b * 4 + hsel * 2 + 0) * 256 + cbase + t, S);
    atomicAdd(st0 + (size_t)(b * 4 + hsel * 2 + 1) * 256 + cbase + t, S2);
  }
}

// ---- k_uv: [bn0 closed-form preamble] U' = c0s*U + c0t ; V' = c0s*V (f16)
// grid 256 x 256 thr, 16 elems/thread.
__global__ __launch_bounds__(256) void k_uv(const float* __restrict__ U,
                                            const float* __restrict__ V,
                                            const float* __restrict__ st0,
                                            const float* __restrict__ gb0,
                                            const float* __restrict__ gg0,
                                            const float* __restrict__ gB0,
                                            _Float16* __restrict__ Up,
                                            _Float16* __restrict__ Vp) {
  __shared__ __align__(16) float sCs[256];
  __shared__ __align__(16) float sCt[256];
  const int t = threadIdx.x;
  {  // BN0 closed form: z = U_i + V_j + b0 over all (b,i,j)
    float su = 0, su2 = 0, sv = 0, sv2 = 0, cross = 0;
    for (int b = 0; b < 64; ++b) {
      float a  = st0[(b * 4 + 0) * 256 + t];
      float a2 = st0[(b * 4 + 1) * 256 + t];
      float v  = st0[(b * 4 + 2) * 256 + t];
      float v2 = st0[(b * 4 + 3) * 256 + t];
      su += a; su2 += a2; sv += v; sv2 += v2; cross += a * v;
    }
    float b0 = gb0[t];
    float sumz  = 64.f * (su + sv) + kM * b0;
    float sumzz = 64.f * (su2 + sv2) + 2.f * cross + 2.f * b0 * 64.f * (su + sv) + kM * b0 * b0;
    float mu = sumz / kM;
    float var = sumzz / kM - mu * mu;
    float sc = gg0[t] * rsqrtf(var + kEps);
    sCs[t] = sc;
    sCt[t] = gB0[t] + sc * (b0 - mu);
  }
  __syncthreads();
#pragma unroll
  for (int it = 0; it < 4; ++it) {
    int e4 = (blockIdx.x * 4096) + it * 1024 + t * 4;
    int c4 = e4 & 255;
    float4_t u = *(const float4_t*)(U + e4);
    float4_t v = *(const float4_t*)(V + e4);
    float4_t s = *(const float4_t*)(sCs + c4);
    float4_t tt = *(const float4_t*)(sCt + c4);
    half4_t hu, hv;
#pragma unroll
    for (int e = 0; e < 4; ++e) {
      hu[e] = (_Float16)(u[e] * s[e] + tt[e]);
      hv[e] = (_Float16)(v[e] * s[e]);
    }
    *(half4_t*)(Up + e4) = hu;
    *(half4_t*)(Vp + e4) = hv;
  }
}

// ---- GEMM1: Z1 = relu(U'+V') @ W1 + b1 -> fp8 (r8 loop + f32 two-half epilogue)
// grid (2048, 2). block 256 = 4 waves (2x2), output tile 128 rows x 128 cols.
__global__ __launch_bounds__(256) void k_gemm1(const _Float16* __restrict__ Up,
                                               const _Float16* __restrict__ Vp,
                                               const _Float16* __restrict__ W1T,
                                               const float* __restrict__ gb1,
                                               unsigned char* __restrict__ Z1,
                                               float* __restrict__ stats1) {
  __shared__ __align__(16) char smem[2 * 128 * 72 * 2];  // 36864 B: sA + sW
  _Float16* sA = (_Float16*)smem;                         // 128 x 72 (a0 slice)
  _Float16* sW = (_Float16*)(smem + 128 * 72 * 2);        // 128 x 72 (W slice)
  float* sO32 = (float*)smem;                             // 64 x 132 f32 (epilogue overlay, 33792 B)

  const int t = threadIdx.x;
  const int bx = blockIdx.x;
  const int n0 = blockIdx.y * 128;
  const int b = bx >> 5;
  const int i0 = (bx & 31) * 2;
  const long R0 = (long)bx * 128;

  const int wid = t >> 6, L = t & 63;
  const int wrow = wid >> 1, wcol = wid & 1;
  const int quad = L >> 4, l15 = L & 15;

  const int prow = t >> 2;          // j index 0..63
  const int pk = (t & 3) * 16;      // k offset within kc-slice

  const _Float16* UpI0 = Up + (size_t)(b * 64 + i0) * 256;
  const _Float16* UpI1 = UpI0 + 256;
  const _Float16* VpJ  = Vp + (size_t)(b * 64 + prow) * 256;

  float4_t acc[4][4];
#pragma unroll
  for (int mt = 0; mt < 4; ++mt)
#pragma unroll
    for (int nt = 0; nt < 4; ++nt) acc[mt][nt] = (float4_t){0.f, 0.f, 0.f, 0.f};

  for (int kc = 0; kc < 4; ++kc) {
    __syncthreads();
    {
      const int kg = kc * 64 + pk;
      half8 va = *(const half8*)(VpJ + kg);
      half8 vb = *(const half8*)(VpJ + kg + 8);
      half8 u0a = *(const half8*)(UpI0 + kg);
      half8 u0b = *(const half8*)(UpI0 + kg + 8);
      half8 u1a = *(const half8*)(UpI1 + kg);
      half8 u1b = *(const half8*)(UpI1 + kg + 8);
      *(half8*)(sA + prow * 72 + pk)            = relu8(u0a + va);
      *(half8*)(sA + prow * 72 + pk + 8)        = relu8(u0b + vb);
      *(half8*)(sA + (64 + prow) * 72 + pk)     = relu8(u1a + va);
      *(half8*)(sA + (64 + prow) * 72 + pk + 8) = relu8(u1b + vb);
    }
#pragma unroll
    for (int it = 0; it < 4; ++it) {
      int flat = it * 256 + t;
      int row = flat >> 3, c8 = (flat & 7) * 8;
      *(half8*)(sW + row * 72 + c8) =
          *(const half8*)(W1T + (size_t)(n0 + row) * 256 + kc * 64 + c8);
    }
    __syncthreads();
#pragma unroll
    for (int ks = 0; ks < 2; ++ks) {
      const int kk = ks * 32 + quad * 8;
      half8 afr[4];
#pragma unroll
      for (int mt = 0; mt < 4; ++mt)
        afr[mt] = *(const half8*)(sA + (wrow * 64 + mt * 16 + l15) * 72 + kk);
      half8 bfr[4];
#pragma unroll
      for (int nt = 0; nt < 4; ++nt)
        bfr[nt] = *(const half8*)(sW + (wcol * 64 + nt * 16 + l15) * 72 + kk);
#pragma unroll
      for (int mt = 0; mt < 4; ++mt)
#pragma unroll
        for (int nt = 0; nt < 4; ++nt)
          acc[mt][nt] = __builtin_amdgcn_mfma_f32_16x16x32_f16(afr[mt], bfr[nt],
                                                               acc[mt][nt], 0, 0, 0);
    }
  }

  // stats + bias fold (registers only; no LDS)
  const int rep = bx & 31;
#pragma unroll
  for (int nt = 0; nt < 4; ++nt) {
    const int lcol = wcol * 64 + nt * 16 + l15;
    const float b1c = gb1[n0 + lcol];
    float sz = 0.f, szz = 0.f;
#pragma unroll
    for (int mt = 0; mt < 4; ++mt)
#pragma unroll
      for (int r = 0; r < 4; ++r) {
        float z = acc[mt][nt][r] + b1c;
        acc[mt][nt][r] = z;
        sz += z;
        szz += z * z;
      }
    sz += __shfl_xor(sz, 16, 64);
    sz += __shfl_xor(sz, 32, 64);
    szz += __shfl_xor(szz, 16, 64);
    szz += __shfl_xor(szz, 32, 64);
    if (quad == 0) {
      atomicAdd(stats1 + rep * 512 + n0 + lcol, sz);
      atomicAdd(stats1 + rep * 512 + 256 + n0 + lcol, szz);
    }
  }

  // two half-row passes: f32 LDS staging, direct f32->fp8 pack, coalesced stores
#pragma unroll
  for (int p = 0; p < 2; ++p) {
    __syncthreads();
    if (wrow == p) {
#pragma unroll
      for (int nt = 0; nt < 4; ++nt) {
        const int lcol = wcol * 64 + nt * 16 + l15;
#pragma unroll
        for (int mt = 0; mt < 4; ++mt) {
          const int lr = mt * 16 + quad * 4;
#pragma unroll
          for (int r = 0; r < 4; ++r)
            sO32[(lr + r) * 132 + lcol] = acc[mt][nt][r];
        }
      }
    }
    __syncthreads();
#pragma unroll
    for (int it = 0; it < 4; ++it) {
      int cid = it * 256 + t;
      int row = cid >> 4, ch = (cid & 15) * 8;
      uint2_t o = pack_fp8_from_f32(sO32 + row * 132 + ch);
      *(uint2_t*)(Z1 + (size_t)(R0 + p * 64 + row) * 256 + n0 + ch) = o;
    }
  }
}

// ---- GEMM2: [bn1 preamble, f16 consts] a1 = relu(bn1(Z1_fp8)) staged f16
//      (packed-f16 math), z2 = a1 @ W2 (f16 MFMA) -> fp8 Z2 (f32 epilogue) + stats
__global__ __launch_bounds__(256) void k_gemm2(const unsigned char* __restrict__ Z1,
                                               const _Float16* __restrict__ W2T,
                                               const float* __restrict__ st1,
                                               const float* __restrict__ gg1,
                                               const float* __restrict__ gB1,
                                               const float* __restrict__ gb2,
                                               unsigned char* __restrict__ Z2,
                                               float* __restrict__ stats2) {
  __shared__ __align__(16) char smem[2 * 128 * 72 * 2];  // 36864 B
  _Float16* sA = (_Float16*)smem;                         // 128 x 72
  _Float16* sW = (_Float16*)(smem + 128 * 72 * 2);        // 128 x 72
  float* sO32 = (float*)smem;                             // 64 x 132 f32 (epilogue overlay)
  __shared__ __align__(16) _Float16 sSh[256];
  __shared__ __align__(16) _Float16 sTh[256];
  const int t = threadIdx.x;
  const int bx = blockIdx.x;
  const long R0 = (long)bx * 128;

  {  // bn1 preamble (per-block, L2-hot st1); f16 constants for packed math
    float S = 0.f, S2 = 0.f;
#pragma unroll
    for (int rp = 0; rp < 32; ++rp) {
      S += st1[rp * 512 + t];
      S2 += st1[rp * 512 + 256 + t];
    }
    float mu = S / kM;
    float var = S2 / kM - mu * mu;
    float sc = gg1[t] * rsqrtf(var + kEps);
    sSh[t] = (_Float16)sc;
    sTh[t] = (_Float16)(gB1[t] - sc * mu);
  }

  const int wid = t >> 6, L = t & 63;
  const int wrow = wid >> 1, wcol = wid & 1;
  const int quad = L >> 4, l15 = L & 15;

  float4_t acc[4][4];
#pragma unroll
  for (int mt = 0; mt < 4; ++mt)
#pragma unroll
    for (int nt = 0; nt < 4; ++nt) acc[mt][nt] = (float4_t){0.f, 0.f, 0.f, 0.f};

  for (int kc = 0; kc < 4; ++kc) {
    __syncthreads();
#pragma unroll
    for (int it = 0; it < 2; ++it) {
      int flat = it * 256 + t;
      int row = flat >> 3, k8 = (flat & 7) * 8;
      int kg = kc * 64 + k8;
      half8 hs = *(const half8*)(sSh + kg);
      half8 ht = *(const half8*)(sTh + kg);
#pragma unroll
      for (int h = 0; h < 2; ++h) {
        int rr = row + h * 64;
        uint2_t p = *(const uint2_t*)(Z1 + ((size_t)R0 + rr) * 256 + kg);
        half8 hv = unpack_fp8x8(p);
        *(half8*)(sA + rr * 72 + k8) = relu8(hv * hs + ht);
      }
    }
#pragma unroll
    for (int it = 0; it < 4; ++it) {
      int flat = it * 256 + t;
      int row = flat >> 3, k8 = (flat & 7) * 8;
      *(half8*)(sW + row * 72 + k8) =
          *(const half8*)(W2T + (size_t)row * 256 + kc * 64 + k8);
    }
    __syncthreads();
#pragma unroll
    for (int ks = 0; ks < 2; ++ks) {
      const int kk = ks * 32 + quad * 8;
      half8 afr[4];
#pragma unroll
      for (int mt = 0; mt < 4; ++mt)
        afr[mt] = *(const half8*)(sA + (wrow * 64 + mt * 16 + l15) * 72 + kk);
      half8 bfr[4];
#pragma unroll
      for (int nt = 0; nt < 4; ++nt)
        bfr[nt] = *(const half8*)(sW + (wcol * 64 + nt * 16 + l15) * 72 + kk);
#pragma unroll
      for (int mt = 0; mt < 4; ++mt)
#pragma unroll
        for (int nt = 0; nt < 4; ++nt)
          acc[mt][nt] = __builtin_amdgcn_mfma_f32_16x16x32_f16(afr[mt], bfr[nt],
                                                               acc[mt][nt], 0, 0, 0);
    }
  }

  // stats + bias fold (registers only)
  const int rep = bx & 31;
#pragma unroll
  for (int nt = 0; nt < 4; ++nt) {
    const int lcol = wcol * 64 + nt * 16 + l15;
    const float b2c = gb2[lcol];
    float sz = 0.f, szz = 0.f;
#pragma unroll
    for (int mt = 0; mt < 4; ++mt)
#pragma unroll
      for (int r = 0; r < 4; ++r) {
        float z = acc[mt][nt][r] + b2c;
        acc[mt][nt][r] = z;
        sz += z;
        szz += z * z;
      }
    sz += __shfl_xor(sz, 16, 64);
    sz += __shfl_xor(sz, 32, 64);
    szz += __shfl_xor(szz, 16, 64);
    szz += __shfl_xor(szz, 32, 64);
    if (quad == 0) {
      atomicAdd(stats2 + rep * 256 + lcol, sz);
      atomicAdd(stats2 + rep * 256 + 128 + lcol, szz);
    }
  }

  // two half-row passes: f32 LDS staging, direct f32->fp8 pack
#pragma unroll
  for (int p = 0; p < 2; ++p) {
    __syncthreads();
    if (wrow == p) {
#pragma unroll
      for (int nt = 0; nt < 4; ++nt) {
        const int lcol = wcol * 64 + nt * 16 + l15;
#pragma unroll
        for (int mt = 0; mt < 4; ++mt) {
          const int lr = mt * 16 + quad * 4;
#pragma unroll
          for (int r = 0; r < 4; ++r)
            sO32[(lr + r) * 132 + lcol] = acc[mt][nt][r];
        }
      }
    }
    __syncthreads();
#pragma unroll
    for (int it = 0; it < 4; ++it) {
      int cid = it * 256 + t;
      int row = cid >> 4, ch = (cid & 15) * 8;
      uint2_t o = pack_fp8_from_f32(sO32 + row * 132 + ch);
      *(uint2_t*)(Z2 + (size_t)(R0 + p * 64 + row) * 128 + ch) = o;
    }
  }
}

// ---- k_red: [bn2 preamble] stream fp8 Z2, bn2+relu, row-reduce -> sbuf (atomics)
__global__ __launch_bounds__(256) void k_red(const unsigned char* __restrict__ Z2,
                                             const float* __restrict__ st2,
                                             const float* __restrict__ gg2,
                                             const float* __restrict__ gB2,
                                             float* __restrict__ sbuf) {
  __shared__ float sR[256 * 8];
  __shared__ __align__(16) float sS2[128];
  __shared__ __align__(16) float sT2[128];
  const int t = threadIdx.x;
  const int bx = blockIdx.x;
  const int b = bx >> 5;
  const long row0 = (long)bx * 128;

  if (t < 128) {
    float S = 0.f, S2 = 0.f;
#pragma unroll
    for (int rp = 0; rp < 32; ++rp) {
      S += st2[rp * 256 + t];
      S2 += st2[rp * 256 + 128 + t];
    }
    float mu = S / kM;
    float var = S2 / kM - mu * mu;
    float sc = gg2[t] * rsqrtf(var + kEps);
    sS2[t] = sc;
    sT2[t] = gB2[t] - sc * mu;
  }
  __syncthreads();

  const int rr = t >> 4;
  const int c8 = (t & 15) * 8;
  float4_t s0 = *(const float4_t*)(sS2 + c8);
  float4_t s1 = *(const float4_t*)(sS2 + c8 + 4);
  float4_t t0 = *(const float4_t*)(sT2 + c8);
  float4_t t1 = *(const float4_t*)(sT2 + c8 + 4);

  float acc[8];
#pragma unroll
  for (int e = 0; e < 8; ++e) acc[e] = 0.f;
#pragma unroll
  for (int it = 0; it < 8; ++it) {
    long row = row0 + it * 16 + rr;
    uint2_t p = *(const uint2_t*)(Z2 + row * 128 + c8);
    float2_t f0 = __builtin_amdgcn_cvt_pk_f32_fp8((int)p[0], false);
    float2_t f1 = __builtin_amdgcn_cvt_pk_f32_fp8((int)p[0], true);
    float2_t f2 = __builtin_amdgcn_cvt_pk_f32_fp8((int)p[1], false);
    float2_t f3 = __builtin_amdgcn_cvt_pk_f32_fp8((int)p[1], true);
    acc[0] += fmaxf(s0[0] * f0[0] + t0[0], 0.f);
    acc[1] += fmaxf(s0[1] * f0[1] + t0[1], 0.f);
    acc[2] += fmaxf(s0[2] * f1[0] + t0[2], 0.f);
    acc[3] += fmaxf(s0[3] * f1[1] + t0[3], 0.f);
    acc[4] += fmaxf(s1[0] * f2[0] + t1[0], 0.f);
    acc[5] += fmaxf(s1[1] * f2[1] + t1[1], 0.f);
    acc[6] += fmaxf(s1[2] * f3[0] + t1[2], 0.f);
    acc[7] += fmaxf(s1[3] * f3[1] + t1[3], 0.f);
  }
#pragma unroll
  for (int e = 0; e < 8; ++e) sR[t * 8 + e] = acc[e];
  __syncthreads();
  if (t < 128) {
    float S = 0.f;
#pragma unroll
    for (int rr2 = 0; rr2 < 16; ++rr2) S += sR[rr2 * 128 + t];
    atomicAdd(sbuf + b * 128 + t, S);
  }
}

// ---- F-stage GEMM: 64x128 @ 128x128 (+bias). 8 blocks x 256 threads.
template <bool APPLY_BN, bool STATS>
__global__ __launch_bounds__(256) void k_fg(const float* __restrict__ in,
                                            const float* __restrict__ prevStats,
                                            const float* __restrict__ g,
                                            const float* __restrict__ B,
                                            const float* __restrict__ W,
                                            const float* __restrict__ bias,
                                            float* __restrict__ zout,
                                            float* __restrict__ stats) {
  __shared__ __align__(16) float sIn[8 * 128];
  __shared__ __align__(16) float sZ[8 * 128];
  __shared__ __align__(16) float sCs[128];
  __shared__ __align__(16) float sCt[128];
  const int t = threadIdx.x;
  const int r0 = blockIdx.x * 8;

  if (APPLY_BN) {
    if (t < 128) {
      float S = prevStats[t], S2 = prevStats[128 + t];
      float mu = S / 64.f;
      float var = S2 / 64.f - mu * mu;
      float sc = g[t] * rsqrtf(var + kEps);
      sCs[t] = sc;
      sCt[t] = B[t] - sc * mu;
    }
    __syncthreads();
  }
  {
    int flat = t * 4;
    int col = flat & 127;
    float4_t v = *(const float4_t*)(in + (size_t)r0 * 128 + flat);
    if (APPLY_BN) {
      float4_t s = *(const float4_t*)(sCs + col);
      float4_t sh = *(const float4_t*)(sCt + col);
#pragma unroll
      for (int e = 0; e < 4; ++e) v[e] = fmaxf(s[e] * v[e] + sh[e], 0.f);
    }
    *(float4_t*)(sIn + flat) = v;
  }
  __syncthreads();

  const int r = t >> 5;
  const int c4 = (t & 31) * 4;
  float4_t acc = *(const float4_t*)(bias + c4);
  for (int k = 0; k < 128; ++k) {
    float xv = sIn[r * 128 + k];
    float4_t w = *(const float4_t*)(W + (size_t)k * 128 + c4);
#pragma unroll
    for (int e = 0; e < 4; ++e) acc[e] += xv * w[e];
  }
  *(float4_t*)(zout + (size_t)(r0 + r) * 128 + c4) = acc;

  if (STATS) {
    *(float4_t*)(sZ + r * 128 + c4) = acc;
    __syncthreads();
    if (t < 128) {
      float S = 0.f, S2 = 0.f;
#pragma unroll
      for (int rr = 0; rr < 8; ++rr) {
        float z = sZ[rr * 128 + t];
        S += z;
        S2 += z * z;
      }
      atomicAdd(stats + t, S);
      atomicAdd(stats + 128 + t, S2);
    }
  }
}

extern "C" void kernel_launch(void* const* d_in, const int* in_sizes, int n_in,
                              void* d_out, int out_size, void* d_ws, size_t ws_size,
                              hipStream_t stream) {
  (void)in_sizes; (void)n_in; (void)out_size; (void)ws_size;
  const float* x   = (const float*)d_in[0];
  const float* gW0 = (const float*)d_in[1];
  const float* gb0 = (const float*)d_in[2];
  const float* gg0 = (const float*)d_in[3];
  const float* gB0 = (const float*)d_in[4];
  const float* gW1 = (const float*)d_in[5];
  const float* gb1 = (const float*)d_in[6];
  const float* gg1 = (const float*)d_in[7];
  const float* gB1 = (const float*)d_in[8];
  const float* gW2 = (const float*)d_in[9];
  const float* gb2 = (const float*)d_in[10];
  const float* gg2 = (const float*)d_in[11];
  const float* gB2 = (const float*)d_in[12];
  const float* fW0 = (const float*)d_in[13];
  const float* fb0 = (const float*)d_in[14];
  const float* fg0 = (const float*)d_in[15];
  const float* fB0 = (const float*)d_in[16];
  const float* fW1 = (const float*)d_in[17];
  const float* fb1 = (const float*)d_in[18];
  const float* fg1 = (const float*)d_in[19];
  const float* fB1 = (const float*)d_in[20];
  const float* foW = (const float*)d_in[21];
  const float* fob = (const float*)d_in[22];
  float* out = (float*)d_out;

  char* ws = (char*)d_ws;
  float*    U    = (float*)(ws + OFF_U);
  float*    V    = (float*)(ws + OFF_V);
  _Float16* Up   = (_Float16*)(ws + OFF_UP);
  _Float16* Vp   = (_Float16*)(ws + OFF_VP);
  _Float16* W1T  = (_Float16*)(ws + OFF_W1T);
  _Float16* W2T  = (_Float16*)(ws + OFF_W2T);
  unsigned char* Z1 = (unsigned char*)(ws + OFF_Z1);
  float*    st0  = (float*)(ws + OFF_ST0);
  float*    st1  = (float*)(ws + OFF_ST1);
  float*    st2  = (float*)(ws + OFF_ST2);
  float*    sbuf = (float*)(ws + OFF_SB);
  float*    fst0 = (float*)(ws + OFF_FST0);
  float*    fst1 = (float*)(ws + OFF_FST1);
  float*    fz0  = (float*)(ws + OFF_FZ0);
  float*    fz1  = (float*)(ws + OFF_FZ1);
  unsigned char* Z2 = (unsigned char*)(ws + OFF_Z2);

  // 1: transpose weights + zero stats region
  k_wt<<<386, 256, 0, stream>>>(gW1, gW2, W1T, W2T, st0);
  // 2: U/V + fused per-b column stats
  k_prep<<<dim3(128, 4), 256, 0, stream>>>(x, gW0, U, V, st0);
  // 3: f16 U'/V' (+bn0 closed-form preamble)
  k_uv<<<256, 256, 0, stream>>>(U, V, st0, gb0, gg0, gB0, Up, Vp);
  // 4: GEMM1 -> fp8 Z1
  k_gemm1<<<dim3(2048, 2), 256, 0, stream>>>(Up, Vp, W1T, gb1, Z1, st1);
  // 5: GEMM2 (+bn1 preamble) -> fp8 Z2
  k_gemm2<<<2048, 256, 0, stream>>>(Z1, W2T, st1, gg1, gB1, gb2, Z2, st2);
  // 6: reduce (+bn2 preamble)
  k_red<<<2048, 256, 0, stream>>>(Z2, st2, gg2, gB2, sbuf);
  // 7-9: F stage (bn folds fused as preambles)
  k_fg<false, true><<<8, 256, 0, stream>>>(sbuf, nullptr, nullptr, nullptr,
                                           fW0, fb0, fz0, fst0);
  k_fg<true, true><<<8, 256, 0, stream>>>(fz0, fst0, fg0, fB0,
                                          fW1, fb1, fz1, fst1);
  k_fg<true, false><<<8, 256, 0, stream>>>(fz1, fst1, fg1, fB1,
                                           foW, fob, out, nullptr);
}

// Round 15
// 273.906 us; speedup vs baseline: 1.0969x; 1.0969x over previous
//
#include <hip/hip_runtime.h>

// RelationNetwork fused pipeline for MI355X (gfx950).
// B=64, N=64, D=64, T=128, HG=256, HF=128, OUT=128. M = B*N*N = 262144 pair rows.
//
// Pipeline (9 dispatches):
//  k_wt     : gW1->W1T, gW2->W2T (f16 [n][k]) + zero stats region
//  k_prep   : U = x@W0[:64], V = x@W0[64:]  (fp32) + fused per-b column stats -> st0
//  k_uv     : [bn0 closed-form preamble] U' = c0s*U + c0t, V' = c0s*V (f16)
//  k_gemm1  : Z1 = relu(U'+V') @ W1 + b1 -> fp8 (r8 loop, r13 single-pass epilogue)
//  k_gemm2  : [bn1 preamble] a1 = relu(bn1(Z1_fp8)) staged f16 (packed math),
//             z2 = a1 @ W2 (f16 MFMA) -> fp8 Z2 (r13 epilogue) + stats
//  k_red    : [bn2 preamble] stream fp8 Z2, bn2+relu, row-reduce -> sbuf
//  k_fg x3  : F MLP GEMMs (bn-fold preambles, 8-block parallel)
//
// Lessons encoded:
//  - r5/r9/r10: gemm1 loop-structure changes fail 3x. r8 loop = local optimum.
//  - r6: a0 precompute into LDS removes VALU from MFMA loop (89->70 us).
//  - r7: dispatch gaps ~2.4us each; 1-block BN kernels fused into consumers.
//  - r11: one fp8 quant per tensor per hop is the accuracy budget.
//  - r13: packed-f16 staging in gemm2 (-8us).
//  - r14: f32 two-half epilogue REGRESSES (70.6->86.2us): half the waves idle
//    per pass + 4 extra barriers; occupancy 27.5->19.6%. Epilogue barrier
//    structure > epilogue VALU. Single-pass f16 epilogue is the right shape.

typedef _Float16 half8 __attribute__((ext_vector_type(8)));
typedef _Float16 half4_t __attribute__((ext_vector_type(4)));
typedef __fp16 fp16x2 __attribute__((ext_vector_type(2)));
typedef float float4_t __attribute__((ext_vector_type(4)));
typedef float float2_t __attribute__((ext_vector_type(2)));
typedef unsigned int uint2_t __attribute__((ext_vector_type(2)));

static constexpr float kEps = 1e-5f;
static constexpr float kM = 262144.f;

// ---- workspace layout (bytes) ----
static constexpr size_t OFF_U   = 0;                                  // 4096*256 f32
static constexpr size_t OFF_V   = OFF_U  + (size_t)4096*256*4;
static constexpr size_t OFF_UP  = OFF_V  + (size_t)4096*256*4;        // f16
static constexpr size_t OFF_VP  = OFF_UP + (size_t)4096*256*2;
static constexpr size_t OFF_W1T = OFF_VP + (size_t)4096*256*2;        // 256x256 f16 [n][k]
static constexpr size_t OFF_W2T = OFF_W1T + (size_t)256*256*2;        // 128x256 f16 [n][k]
static constexpr size_t OFF_Z1  = OFF_W2T + (size_t)128*256*2;        // 262144x256 fp8
// ---- zeroed region start (zeroed by k_wt every launch) ----
static constexpr size_t OFF_ST0 = OFF_Z1 + (size_t)262144*256;        // 64*4*256 f32 (atomics)
static constexpr size_t OFF_ST1 = OFF_ST0 + (size_t)64*4*256*4;       // 32*512 f32
static constexpr size_t OFF_ST2 = OFF_ST1 + (size_t)32*512*4;         // 32*256 f32
static constexpr size_t OFF_SB  = OFF_ST2 + (size_t)32*256*4;         // 64*128 f32
static constexpr size_t OFF_FST0 = OFF_SB + (size_t)64*128*4;         // 256 f32
static constexpr size_t OFF_FST1 = OFF_FST0 + 1024;                   // 256 f32
static constexpr int ZERO_FLOATS = (64*4*256 + 32*512 + 32*256 + 64*128 + 256 + 256);
// ---- end zeroed region ----
static constexpr size_t OFF_FZ0  = OFF_FST1 + 1024;                   // 64*128 f32
static constexpr size_t OFF_FZ1  = OFF_FZ0 + (size_t)64*128*4;
static constexpr size_t OFF_Z2   = OFF_FZ1 + (size_t)64*128*4;        // 262144x128 fp8

static __device__ inline half8 relu8(half8 s) {
#pragma unroll
  for (int e = 0; e < 8; ++e) s[e] = s[e] > (_Float16)0 ? s[e] : (_Float16)0;
  return s;
}

// pack 8 f16 -> 8 fp8 e4m3 bytes (via f32)
static __device__ inline uint2_t pack_fp8x8(half8 hv) {
  int lo = 0, hi = 0;
  lo = __builtin_amdgcn_cvt_pk_fp8_f32((float)hv[0], (float)hv[1], lo, false);
  lo = __builtin_amdgcn_cvt_pk_fp8_f32((float)hv[2], (float)hv[3], lo, true);
  hi = __builtin_amdgcn_cvt_pk_fp8_f32((float)hv[4], (float)hv[5], hi, false);
  hi = __builtin_amdgcn_cvt_pk_fp8_f32((float)hv[6], (float)hv[7], hi, true);
  uint2_t o = {(unsigned)lo, (unsigned)hi};
  return o;
}

// unpack 8 fp8 e4m3 bytes -> 8 f16 (via f32, packed cvt)
static __device__ inline half8 unpack_fp8x8(uint2_t p) {
  float2_t f0 = __builtin_amdgcn_cvt_pk_f32_fp8((int)p[0], false);
  float2_t f1 = __builtin_amdgcn_cvt_pk_f32_fp8((int)p[0], true);
  float2_t f2 = __builtin_amdgcn_cvt_pk_f32_fp8((int)p[1], false);
  float2_t f3 = __builtin_amdgcn_cvt_pk_f32_fp8((int)p[1], true);
  fp16x2 h0 = __builtin_amdgcn_cvt_pkrtz(f0[0], f0[1]);
  fp16x2 h1 = __builtin_amdgcn_cvt_pkrtz(f1[0], f1[1]);
  fp16x2 h2 = __builtin_amdgcn_cvt_pkrtz(f2[0], f2[1]);
  fp16x2 h3 = __builtin_amdgcn_cvt_pkrtz(f3[0], f3[1]);
  half8 hv = {(_Float16)h0[0], (_Float16)h0[1], (_Float16)h1[0], (_Float16)h1[1],
              (_Float16)h2[0], (_Float16)h2[1], (_Float16)h3[0], (_Float16)h3[1]};
  return hv;
}

// ---- W transpose/convert + zero the stats region
__global__ __launch_bounds__(256) void k_wt(const float* __restrict__ gW1,
                                            const float* __restrict__ gW2,
                                            _Float16* __restrict__ W1T,
                                            _Float16* __restrict__ W2T,
                                            float* __restrict__ zbuf) {
  int idx = blockIdx.x * 256 + threadIdx.x;
  if (idx < 65536) {
    int n = idx >> 8, k = idx & 255;
    W1T[idx] = (_Float16)gW1[k * 256 + n];
  } else if (idx < 98304) {
    int j = idx - 65536;
    int n = j >> 8, k = j & 255;
    W2T[j] = (_Float16)gW2[k * 128 + n];
  }
  if (idx < ZERO_FLOATS) zbuf[idx] = 0.f;
}

// ---- U = x @ W0[0:64,:], V = x @ W0[64:128,:]  (fp32) + fused column stats -> st0
__global__ __launch_bounds__(256) void k_prep(const float* __restrict__ x,
                                              const float* __restrict__ gW0,
                                              float* __restrict__ U,
                                              float* __restrict__ V,
                                              float* __restrict__ st0) {
  __shared__ __align__(16) float sX[32 * 64];
  __shared__ __align__(16) float sZ[32 * 128];
  int t = threadIdx.x;
  int p0 = blockIdx.x * 32;
  int by = blockIdx.y;
  int hsel = by >> 1;
  int cbase = (by & 1) * 128;
#pragma unroll
  for (int it = 0; it < 2; ++it) {
    int f4 = (it * 256 + t) * 4;
    *(float4_t*)(sX + f4) = *(const float4_t*)(x + (size_t)p0 * 64 + f4);
  }
  __syncthreads();
  int r = t >> 3, cg = (t & 7) * 16;
  const float* Wb = gW0 + (size_t)(hsel * 64) * 256 + cbase + cg;
  float acc[16];
#pragma unroll
  for (int j = 0; j < 16; ++j) acc[j] = 0.f;
  for (int k = 0; k < 64; ++k) {
    float xv = sX[r * 64 + k];
    const float4_t* wr = (const float4_t*)(Wb + (size_t)k * 256);
    float4_t w0 = wr[0], w1 = wr[1], w2 = wr[2], w3 = wr[3];
#pragma unroll
    for (int j = 0; j < 4; ++j) {
      acc[j]      += xv * w0[j];
      acc[4 + j]  += xv * w1[j];
      acc[8 + j]  += xv * w2[j];
      acc[12 + j] += xv * w3[j];
    }
  }
  float* outp = (hsel ? V : U) + (size_t)(p0 + r) * 256 + cbase + cg;
#pragma unroll
  for (int q = 0; q < 4; ++q) {
    float4_t o = {acc[q * 4], acc[q * 4 + 1], acc[q * 4 + 2], acc[q * 4 + 3]};
    *(float4_t*)(outp + q * 4) = o;
  }
#pragma unroll
  for (int j = 0; j < 16; ++j) sZ[r * 128 + cg + j] = acc[j];
  __syncthreads();
  if (t < 128) {
    float S = 0.f, S2 = 0.f;
#pragma unroll
    for (int rr = 0; rr < 32; ++rr) {
      float z = sZ[rr * 128 + t];
      S += z;
      S2 += z * z;
    }
    int b = blockIdx.x >> 1;
    atomicAdd(st0 + (size_t)(b * 4 + hsel * 2 + 0) * 256 + cbase + t, S);
    atomicAdd(st0 + (size_t)(b * 4 + hsel * 2 + 1) * 256 + cbase + t, S2);
  }
}

// ---- k_uv: [bn0 closed-form preamble] U' = c0s*U + c0t ; V' = c0s*V (f16)
// grid 256 x 256 thr, 16 elems/thread.
__global__ __launch_bounds__(256) void k_uv(const float* __restrict__ U,
                                            const float* __restrict__ V,
                                            const float* __restrict__ st0,
                                            const float* __restrict__ gb0,
                                            const float* __restrict__ gg0,
                                            const float* __restrict__ gB0,
                                            _Float16* __restrict__ Up,
                                            _Float16* __restrict__ Vp) {
  __shared__ __align__(16) float sCs[256];
  __shared__ __align__(16) float sCt[256];
  const int t = threadIdx.x;
  {  // BN0 closed form: z = U_i + V_j + b0 over all (b,i,j)
    float su = 0, su2 = 0, sv = 0, sv2 = 0, cross = 0;
    for (int b = 0; b < 64; ++b) {
      float a  = st0[(b * 4 + 0) * 256 + t];
      float a2 = st0[(b * 4 + 1) * 256 + t];
      float v  = st0[(b * 4 + 2) * 256 + t];
      float v2 = st0[(b * 4 + 3) * 256 + t];
      su += a; su2 += a2; sv += v; sv2 += v2; cross += a * v;
    }
    float b0 = gb0[t];
    float sumz  = 64.f * (su + sv) + kM * b0;
    float sumzz = 64.f * (su2 + sv2) + 2.f * cross + 2.f * b0 * 64.f * (su + sv) + kM * b0 * b0;
    float mu = sumz / kM;
    float var = sumzz / kM - mu * mu;
    float sc = gg0[t] * rsqrtf(var + kEps);
    sCs[t] = sc;
    sCt[t] = gB0[t] + sc * (b0 - mu);
  }
  __syncthreads();
#pragma unroll
  for (int it = 0; it < 4; ++it) {
    int e4 = (blockIdx.x * 4096) + it * 1024 + t * 4;
    int c4 = e4 & 255;
    float4_t u = *(const float4_t*)(U + e4);
    float4_t v = *(const float4_t*)(V + e4);
    float4_t s = *(const float4_t*)(sCs + c4);
    float4_t tt = *(const float4_t*)(sCt + c4);
    half4_t hu, hv;
#pragma unroll
    for (int e = 0; e < 4; ++e) {
      hu[e] = (_Float16)(u[e] * s[e] + tt[e]);
      hv[e] = (_Float16)(v[e] * s[e]);
    }
    *(half4_t*)(Up + e4) = hu;
    *(half4_t*)(Vp + e4) = hv;
  }
}

// ---- GEMM1 (r8 loop + r13 epilogue — known-good): Z1 = relu(U'+V') @ W1 + b1 -> fp8
// grid (2048, 2). block 256 = 4 waves (2x2), output tile 128 rows x 128 cols.
__global__ __launch_bounds__(256) void k_gemm1(const _Float16* __restrict__ Up,
                                               const _Float16* __restrict__ Vp,
                                               const _Float16* __restrict__ W1T,
                                               const float* __restrict__ gb1,
                                               unsigned char* __restrict__ Z1,
                                               float* __restrict__ stats1) {
  __shared__ __align__(16) char smem[2 * 128 * 72 * 2];  // 36864 B: sA + sW
  _Float16* sA = (_Float16*)smem;                         // 128 x 72 (a0 slice)
  _Float16* sW = (_Float16*)(smem + 128 * 72 * 2);        // 128 x 72 (W slice)
  _Float16* sO = (_Float16*)smem;                         // 128 x 136 (epilogue overlay)

  const int t = threadIdx.x;
  const int bx = blockIdx.x;
  const int n0 = blockIdx.y * 128;
  const int b = bx >> 5;
  const int i0 = (bx & 31) * 2;
  const long R0 = (long)bx * 128;

  const int wid = t >> 6, L = t & 63;
  const int wrow = wid >> 1, wcol = wid & 1;
  const int quad = L >> 4, l15 = L & 15;

  const int prow = t >> 2;          // j index 0..63
  const int pk = (t & 3) * 16;      // k offset within kc-slice

  const _Float16* UpI0 = Up + (size_t)(b * 64 + i0) * 256;
  const _Float16* UpI1 = UpI0 + 256;
  const _Float16* VpJ  = Vp + (size_t)(b * 64 + prow) * 256;

  float4_t acc[4][4];
#pragma unroll
  for (int mt = 0; mt < 4; ++mt)
#pragma unroll
    for (int nt = 0; nt < 4; ++nt) acc[mt][nt] = (float4_t){0.f, 0.f, 0.f, 0.f};

  for (int kc = 0; kc < 4; ++kc) {
    __syncthreads();
    {
      const int kg = kc * 64 + pk;
      half8 va = *(const half8*)(VpJ + kg);
      half8 vb = *(const half8*)(VpJ + kg + 8);
      half8 u0a = *(const half8*)(UpI0 + kg);
      half8 u0b = *(const half8*)(UpI0 + kg + 8);
      half8 u1a = *(const half8*)(UpI1 + kg);
      half8 u1b = *(const half8*)(UpI1 + kg + 8);
      *(half8*)(sA + prow * 72 + pk)            = relu8(u0a + va);
      *(half8*)(sA + prow * 72 + pk + 8)        = relu8(u0b + vb);
      *(half8*)(sA + (64 + prow) * 72 + pk)     = relu8(u1a + va);
      *(half8*)(sA + (64 + prow) * 72 + pk + 8) = relu8(u1b + vb);
    }
#pragma unroll
    for (int it = 0; it < 4; ++it) {
      int flat = it * 256 + t;
      int row = flat >> 3, c8 = (flat & 7) * 8;
      *(half8*)(sW + row * 72 + c8) =
          *(const half8*)(W1T + (size_t)(n0 + row) * 256 + kc * 64 + c8);
    }
    __syncthreads();
#pragma unroll
    for (int ks = 0; ks < 2; ++ks) {
      const int kk = ks * 32 + quad * 8;
      half8 afr[4];
#pragma unroll
      for (int mt = 0; mt < 4; ++mt)
        afr[mt] = *(const half8*)(sA + (wrow * 64 + mt * 16 + l15) * 72 + kk);
      half8 bfr[4];
#pragma unroll
      for (int nt = 0; nt < 4; ++nt)
        bfr[nt] = *(const half8*)(sW + (wcol * 64 + nt * 16 + l15) * 72 + kk);
#pragma unroll
      for (int mt = 0; mt < 4; ++mt)
#pragma unroll
        for (int nt = 0; nt < 4; ++nt)
          acc[mt][nt] = __builtin_amdgcn_mfma_f32_16x16x32_f16(afr[mt], bfr[nt],
                                                               acc[mt][nt], 0, 0, 0);
    }
  }

  __syncthreads();
  const int rep = bx & 31;
#pragma unroll
  for (int nt = 0; nt < 4; ++nt) {
    const int lcol = wcol * 64 + nt * 16 + l15;
    const float b1c = gb1[n0 + lcol];
    float sz = 0.f, szz = 0.f;
#pragma unroll
    for (int mt = 0; mt < 4; ++mt) {
      const int lrow = wrow * 64 + mt * 16 + quad * 4;
#pragma unroll
      for (int r = 0; r < 4; ++r) {
        float z = acc[mt][nt][r] + b1c;
        sO[(lrow + r) * 136 + lcol] = (_Float16)z;
        sz += z;
        szz += z * z;
      }
    }
    sz += __shfl_xor(sz, 16, 64);
    sz += __shfl_xor(sz, 32, 64);
    szz += __shfl_xor(szz, 16, 64);
    szz += __shfl_xor(szz, 32, 64);
    if (quad == 0) {
      atomicAdd(stats1 + rep * 512 + n0 + lcol, sz);
      atomicAdd(stats1 + rep * 512 + 256 + n0 + lcol, szz);
    }
  }
  __syncthreads();
#pragma unroll
  for (int it = 0; it < 8; ++it) {
    int cid = it * 256 + t;
    int row = cid >> 4, ch = (cid & 15) * 8;
    half8 hv = *(const half8*)(sO + row * 136 + ch);
    uint2_t o = pack_fp8x8(hv);
    *(uint2_t*)(Z1 + (size_t)(R0 + row) * 256 + n0 + ch) = o;
  }
}

// ---- GEMM2: [bn1 preamble, f16 consts] a1 = relu(bn1(Z1_fp8)) staged f16
//      (packed-f16 math), z2 = a1 @ W2 (f16 MFMA) -> fp8 Z2 + stats (r13 epilogue)
__global__ __launch_bounds__(256) void k_gemm2(const unsigned char* __restrict__ Z1,
                                               const _Float16* __restrict__ W2T,
                                               const float* __restrict__ st1,
                                               const float* __restrict__ gg1,
                                               const float* __restrict__ gB1,
                                               const float* __restrict__ gb2,
                                               unsigned char* __restrict__ Z2,
                                               float* __restrict__ stats2) {
  __shared__ __align__(16) char smem[2 * 128 * 72 * 2];  // 36864 B
  _Float16* sA = (_Float16*)smem;                         // 128 x 72
  _Float16* sW = (_Float16*)(smem + 128 * 72 * 2);        // 128 x 72
  _Float16* sO = (_Float16*)smem;                         // 128 x 136 (epilogue overlay)
  __shared__ __align__(16) _Float16 sSh[256];
  __shared__ __align__(16) _Float16 sTh[256];
  const int t = threadIdx.x;
  const int bx = blockIdx.x;
  const long R0 = (long)bx * 128;

  {  // bn1 preamble (per-block, L2-hot st1); f16 constants for packed math
    float S = 0.f, S2 = 0.f;
#pragma unroll
    for (int rp = 0; rp < 32; ++rp) {
      S += st1[rp * 512 + t];
      S2 += st1[rp * 512 + 256 + t];
    }
    float mu = S / kM;
    float var = S2 / kM - mu * mu;
    float sc = gg1[t] * rsqrtf(var + kEps);
    sSh[t] = (_Float16)sc;
    sTh[t] = (_Float16)(gB1[t] - sc * mu);
  }

  const int wid = t >> 6, L = t & 63;
  const int wrow = wid >> 1, wcol = wid & 1;
  const int quad = L >> 4, l15 = L & 15;

  float4_t acc[4][4];
#pragma unroll
  for (int mt = 0; mt < 4; ++mt)
#pragma unroll
    for (int nt = 0; nt < 4; ++nt) acc[mt][nt] = (float4_t){0.f, 0.f, 0.f, 0.f};

  for (int kc = 0; kc < 4; ++kc) {
    __syncthreads();
#pragma unroll
    for (int it = 0; it < 2; ++it) {
      int flat = it * 256 + t;
      int row = flat >> 3, k8 = (flat & 7) * 8;
      int kg = kc * 64 + k8;
      half8 hs = *(const half8*)(sSh + kg);
      half8 ht = *(const half8*)(sTh + kg);
#pragma unroll
      for (int h = 0; h < 2; ++h) {
        int rr = row + h * 64;
        uint2_t p = *(const uint2_t*)(Z1 + ((size_t)R0 + rr) * 256 + kg);
        half8 hv = unpack_fp8x8(p);
        *(half8*)(sA + rr * 72 + k8) = relu8(hv * hs + ht);
      }
    }
#pragma unroll
    for (int it = 0; it < 4; ++it) {
      int flat = it * 256 + t;
      int row = flat >> 3, k8 = (flat & 7) * 8;
      *(half8*)(sW + row * 72 + k8) =
          *(const half8*)(W2T + (size_t)row * 256 + kc * 64 + k8);
    }
    __syncthreads();
#pragma unroll
    for (int ks = 0; ks < 2; ++ks) {
      const int kk = ks * 32 + quad * 8;
      half8 afr[4];
#pragma unroll
      for (int mt = 0; mt < 4; ++mt)
        afr[mt] = *(const half8*)(sA + (wrow * 64 + mt * 16 + l15) * 72 + kk);
      half8 bfr[4];
#pragma unroll
      for (int nt = 0; nt < 4; ++nt)
        bfr[nt] = *(const half8*)(sW + (wcol * 64 + nt * 16 + l15) * 72 + kk);
#pragma unroll
      for (int mt = 0; mt < 4; ++mt)
#pragma unroll
        for (int nt = 0; nt < 4; ++nt)
          acc[mt][nt] = __builtin_amdgcn_mfma_f32_16x16x32_f16(afr[mt], bfr[nt],
                                                               acc[mt][nt], 0, 0, 0);
    }
  }

  __syncthreads();
  const int rep = bx & 31;
#pragma unroll
  for (int nt = 0; nt < 4; ++nt) {
    const int lcol = wcol * 64 + nt * 16 + l15;
    const float b2c = gb2[lcol];
    float sz = 0.f, szz = 0.f;
#pragma unroll
    for (int mt = 0; mt < 4; ++mt) {
      const int lrow = wrow * 64 + mt * 16 + quad * 4;
#pragma unroll
      for (int r = 0; r < 4; ++r) {
        float z = acc[mt][nt][r] + b2c;
        sO[(lrow + r) * 136 + lcol] = (_Float16)z;
        sz += z;
        szz += z * z;
      }
    }
    sz += __shfl_xor(sz, 16, 64);
    sz += __shfl_xor(sz, 32, 64);
    szz += __shfl_xor(szz, 16, 64);
    szz += __shfl_xor(szz, 32, 64);
    if (quad == 0) {
      atomicAdd(stats2 + rep * 256 + lcol, sz);
      atomicAdd(stats2 + rep * 256 + 128 + lcol, szz);
    }
  }
  __syncthreads();
#pragma unroll
  for (int it = 0; it < 8; ++it) {
    int cid = it * 256 + t;
    int row = cid >> 4, ch = (cid & 15) * 8;
    half8 hv = *(const half8*)(sO + row * 136 + ch);
    uint2_t o = pack_fp8x8(hv);
    *(uint2_t*)(Z2 + (size_t)(R0 + row) * 128 + ch) = o;
  }
}

// ---- k_red: [bn2 preamble] stream fp8 Z2, bn2+relu, row-reduce -> sbuf (atomics)
__global__ __launch_bounds__(256) void k_red(const unsigned char* __restrict__ Z2,
                                             const float* __restrict__ st2,
                                             const float* __restrict__ gg2,
                                             const float* __restrict__ gB2,
                                             float* __restrict__ sbuf) {
  __shared__ float sR[256 * 8];
  __shared__ __align__(16) float sS2[128];
  __shared__ __align__(16) float sT2[128];
  const int t = threadIdx.x;
  const int bx = blockIdx.x;
  const int b = bx >> 5;
  const long row0 = (long)bx * 128;

  if (t < 128) {
    float S = 0.f, S2 = 0.f;
#pragma unroll
    for (int rp = 0; rp < 32; ++rp) {
      S += st2[rp * 256 + t];
      S2 += st2[rp * 256 + 128 + t];
    }
    float mu = S / kM;
    float var = S2 / kM - mu * mu;
    float sc = gg2[t] * rsqrtf(var + kEps);
    sS2[t] = sc;
    sT2[t] = gB2[t] - sc * mu;
  }
  __syncthreads();

  const int rr = t >> 4;
  const int c8 = (t & 15) * 8;
  float4_t s0 = *(const float4_t*)(sS2 + c8);
  float4_t s1 = *(const float4_t*)(sS2 + c8 + 4);
  float4_t t0 = *(const float4_t*)(sT2 + c8);
  float4_t t1 = *(const float4_t*)(sT2 + c8 + 4);

  float acc[8];
#pragma unroll
  for (int e = 0; e < 8; ++e) acc[e] = 0.f;
#pragma unroll
  for (int it = 0; it < 8; ++it) {
    long row = row0 + it * 16 + rr;
    uint2_t p = *(const uint2_t*)(Z2 + row * 128 + c8);
    float2_t f0 = __builtin_amdgcn_cvt_pk_f32_fp8((int)p[0], false);
    float2_t f1 = __builtin_amdgcn_cvt_pk_f32_fp8((int)p[0], true);
    float2_t f2 = __builtin_amdgcn_cvt_pk_f32_fp8((int)p[1], false);
    float2_t f3 = __builtin_amdgcn_cvt_pk_f32_fp8((int)p[1], true);
    acc[0] += fmaxf(s0[0] * f0[0] + t0[0], 0.f);
    acc[1] += fmaxf(s0[1] * f0[1] + t0[1], 0.f);
    acc[2] += fmaxf(s0[2] * f1[0] + t0[2], 0.f);
    acc[3] += fmaxf(s0[3] * f1[1] + t0[3], 0.f);
    acc[4] += fmaxf(s1[0] * f2[0] + t1[0], 0.f);
    acc[5] += fmaxf(s1[1] * f2[1] + t1[1], 0.f);
    acc[6] += fmaxf(s1[2] * f3[0] + t1[2], 0.f);
    acc[7] += fmaxf(s1[3] * f3[1] + t1[3], 0.f);
  }
#pragma unroll
  for (int e = 0; e < 8; ++e) sR[t * 8 + e] = acc[e];
  __syncthreads();
  if (t < 128) {
    float S = 0.f;
#pragma unroll
    for (int rr2 = 0; rr2 < 16; ++rr2) S += sR[rr2 * 128 + t];
    atomicAdd(sbuf + b * 128 + t, S);
  }
}

// ---- F-stage GEMM: 64x128 @ 128x128 (+bias). 8 blocks x 256 threads.
template <bool APPLY_BN, bool STATS>
__global__ __launch_bounds__(256) void k_fg(const float* __restrict__ in,
                                            const float* __restrict__ prevStats,
                                            const float* __restrict__ g,
                                            const float* __restrict__ B,
                                            const float* __restrict__ W,
                                            const float* __restrict__ bias,
                                            float* __restrict__ zout,
                                            float* __restrict__ stats) {
  __shared__ __align__(16) float sIn[8 * 128];
  __shared__ __align__(16) float sZ[8 * 128];
  __shared__ __align__(16) float sCs[128];
  __shared__ __align__(16) float sCt[128];
  const int t = threadIdx.x;
  const int r0 = blockIdx.x * 8;

  if (APPLY_BN) {
    if (t < 128) {
      float S = prevStats[t], S2 = prevStats[128 + t];
      float mu = S / 64.f;
      float var = S2 / 64.f - mu * mu;
      float sc = g[t] * rsqrtf(var + kEps);
      sCs[t] = sc;
      sCt[t] = B[t] - sc * mu;
    }
    __syncthreads();
  }
  {
    int flat = t * 4;
    int col = flat & 127;
    float4_t v = *(const float4_t*)(in + (size_t)r0 * 128 + flat);
    if (APPLY_BN) {
      float4_t s = *(const float4_t*)(sCs + col);
      float4_t sh = *(const float4_t*)(sCt + col);
#pragma unroll
      for (int e = 0; e < 4; ++e) v[e] = fmaxf(s[e] * v[e] + sh[e], 0.f);
    }
    *(float4_t*)(sIn + flat) = v;
  }
  __syncthreads();

  const int r = t >> 5;
  const int c4 = (t & 31) * 4;
  float4_t acc = *(const float4_t*)(bias + c4);
  for (int k = 0; k < 128; ++k) {
    float xv = sIn[r * 128 + k];
    float4_t w = *(const float4_t*)(W + (size_t)k * 128 + c4);
#pragma unroll
    for (int e = 0; e < 4; ++e) acc[e] += xv * w[e];
  }
  *(float4_t*)(zout + (size_t)(r0 + r) * 128 + c4) = acc;

  if (STATS) {
    *(float4_t*)(sZ + r * 128 + c4) = acc;
    __syncthreads();
    if (t < 128) {
      float S = 0.f, S2 = 0.f;
#pragma unroll
      for (int rr = 0; rr < 8; ++rr) {
        float z = sZ[rr * 128 + t];
        S += z;
        S2 += z * z;
      }
      atomicAdd(stats + t, S);
      atomicAdd(stats + 128 + t, S2);
    }
  }
}

extern "C" void kernel_launch(void* const* d_in, const int* in_sizes, int n_in,
                              void* d_out, int out_size, void* d_ws, size_t ws_size,
                              hipStream_t stream) {
  (void)in_sizes; (void)n_in; (void)out_size; (void)ws_size;
  const float* x   = (const float*)d_in[0];
  const float* gW0 = (const float*)d_in[1];
  const float* gb0 = (const float*)d_in[2];
  const float* gg0 = (const float*)d_in[3];
  const float* gB0 = (const float*)d_in[4];
  const float* gW1 = (const float*)d_in[5];
  const float* gb1 = (const float*)d_in[6];
  const float* gg1 = (const float*)d_in[7];
  const float* gB1 = (const float*)d_in[8];
  const float* gW2 = (const float*)d_in[9];
  const float* gb2 = (const float*)d_in[10];
  const float* gg2 = (const float*)d_in[11];
  const float* gB2 = (const float*)d_in[12];
  const float* fW0 = (const float*)d_in[13];
  const float* fb0 = (const float*)d_in[14];
  const float* fg0 = (const float*)d_in[15];
  const float* fB0 = (const float*)d_in[16];
  const float* fW1 = (const float*)d_in[17];
  const float* fb1 = (const float*)d_in[18];
  const float* fg1 = (const float*)d_in[19];
  const float* fB1 = (const float*)d_in[20];
  const float* foW = (const float*)d_in[21];
  const float* fob = (const float*)d_in[22];
  float* out = (float*)d_out;

  char* ws = (char*)d_ws;
  float*    U    = (float*)(ws + OFF_U);
  float*    V    = (float*)(ws + OFF_V);
  _Float16* Up   = (_Float16*)(ws + OFF_UP);
  _Float16* Vp   = (_Float16*)(ws + OFF_VP);
  _Float16* W1T  = (_Float16*)(ws + OFF_W1T);
  _Float16* W2T  = (_Float16*)(ws + OFF_W2T);
  unsigned char* Z1 = (unsigned char*)(ws + OFF_Z1);
  float*    st0  = (float*)(ws + OFF_ST0);
  float*    st1  = (float*)(ws + OFF_ST1);
  float*    st2  = (float*)(ws + OFF_ST2);
  float*    sbuf = (float*)(ws + OFF_SB);
  float*    fst0 = (float*)(ws + OFF_FST0);
  float*    fst1 = (float*)(ws + OFF_FST1);
  float*    fz0  = (float*)(ws + OFF_FZ0);
  float*    fz1  = (float*)(ws + OFF_FZ1);
  unsigned char* Z2 = (unsigned char*)(ws + OFF_Z2);

  // 1: transpose weights + zero stats region
  k_wt<<<386, 256, 0, stream>>>(gW1, gW2, W1T, W2T, st0);
  // 2: U/V + fused per-b column stats
  k_prep<<<dim3(128, 4), 256, 0, stream>>>(x, gW0, U, V, st0);
  // 3: f16 U'/V' (+bn0 closed-form preamble)
  k_uv<<<256, 256, 0, stream>>>(U, V, st0, gb0, gg0, gB0, Up, Vp);
  // 4: GEMM1 -> fp8 Z1
  k_gemm1<<<dim3(2048, 2), 256, 0, stream>>>(Up, Vp, W1T, gb1, Z1, st1);
  // 5: GEMM2 (+bn1 preamble) -> fp8 Z2
  k_gemm2<<<2048, 256, 0, stream>>>(Z1, W2T, st1, gg1, gB1, gb2, Z2, st2);
  // 6: reduce (+bn2 preamble)
  k_red<<<2048, 256, 0, stream>>>(Z2, st2, gg2, gB2, sbuf);
  // 7-9: F stage (bn folds fused as preambles)
  k_fg<false, true><<<8, 256, 0, stream>>>(sbuf, nullptr, nullptr, nullptr,
                                           fW0, fb0, fz0, fst0);
  k_fg<true, true><<<8, 256, 0, stream>>>(fz0, fst0, fg0, fB0,
                                          fW1, fb1, fz1, fst1);
  k_fg<true, false><<<8, 256, 0, stream>>>(fz1, fst1, fg1, fB1,
                                           foW, fob, out, nullptr);
}